// Round 1
// 188.524 us; speedup vs baseline: 1.0772x; 1.0772x over previous
//
#include <hip/hip_runtime.h>
#include <hip/hip_fp16.h>

#define N_ITEMS 100000
#define HID 128
#define NNZ_T 1600000
#define RP_BLOCKS 391              // ceil(100001/256) binary-search blocks (placed FIRST)
#define GB_BLOCKS 1563             // ceil(100000/64) gemm blocks
#define SPMM_BLOCKS 2048           // 8 blocks/CU * 256 CU (persistent)
#define WSTRIDE (SPMM_BLOCKS * 4)  // waves in flight

typedef unsigned short ushort_t;
typedef unsigned int uint_t;
typedef short bf16x8 __attribute__((ext_vector_type(8)));
typedef float f32x4 __attribute__((ext_vector_type(4)));

static __device__ __forceinline__ ushort_t f32_to_bf16(float f) {
    uint_t u = __float_as_uint(f);
    uint_t r = (u + 0x7FFFu + ((u >> 16) & 1u)) >> 16;   // RNE
    return (ushort_t)r;
}

// === K1: blocks [0,RP_BLOCKS) build row_ptr; blocks [RP_BLOCKS..) do the GEMM,
// staging W f32->bf16 into LDS themselves (removes the prep kernel + one gap).
// LDS layout: logical short-index L (row*128+k), physical = L ^ ((row&7)<<3)
// -> ds_read_b128 per (nt,kb) hits 8 distinct bank-quads, 2-way (free).
__global__ __launch_bounds__(256) void prep_gemm(
    const float* __restrict__ X, const float* __restrict__ W,
    const float* __restrict__ bias, const int* __restrict__ rows,
    ushort_t* __restrict__ S, int* __restrict__ row_ptr) {
    if (blockIdx.x < RP_BLOCKS) {
        int r = blockIdx.x * 256 + threadIdx.x;
        if (r > N_ITEMS) return;
        int lo = 0, hi = NNZ_T;
        while (lo < hi) {                       // lower_bound(rows, r), rows sorted
            int mid = (lo + hi) >> 1;
            if (rows[mid] < r) lo = mid + 1; else hi = mid;
        }
        row_ptr[r] = lo;
        return;
    }

    __shared__ ushort_t Wl[HID * HID];          // 32 KB bf16, swizzled
    {
        const int t = threadIdx.x;
        const float4* Wf = (const float4*)W;
#pragma unroll
        for (int j = 0; j < 8; ++j) {
            const int gblk = j * 256 + t;       // 16B granule id, 0..2047
            float4 w0 = Wf[gblk * 2];
            float4 w1 = Wf[gblk * 2 + 1];
            bf16x8 v;
            v[0] = (short)f32_to_bf16(w0.x); v[1] = (short)f32_to_bf16(w0.y);
            v[2] = (short)f32_to_bf16(w0.z); v[3] = (short)f32_to_bf16(w0.w);
            v[4] = (short)f32_to_bf16(w1.x); v[5] = (short)f32_to_bf16(w1.y);
            v[6] = (short)f32_to_bf16(w1.z); v[7] = (short)f32_to_bf16(w1.w);
            const int ps = (gblk * 8) ^ (((gblk >> 4) & 7) << 3);  // phys short idx
            *(bf16x8*)&Wl[ps] = v;
        }
    }
    __syncthreads();

    const int lane = threadIdx.x & 63;
    const int wave = threadIdx.x >> 6;
    const int m = lane & 15;
    const int q = lane >> 4;
    const int row0 = (blockIdx.x - RP_BLOCKS) * 64 + wave * 16;

    int arow = row0 + m;
    if (arow >= N_ITEMS) arow = N_ITEMS - 1;    // clamp (stores guarded)

    const int swz = (m & 7) << 3;               // row&7 == m&7 for row = nt*16+m
    f32x4 acc[8] = {};

#pragma unroll
    for (int kb = 0; kb < 4; ++kb) {
        const int k0 = kb * 32 + q * 8;
        float4 a0 = *(const float4*)&X[(size_t)arow * HID + k0];
        float4 a1 = *(const float4*)&X[(size_t)arow * HID + k0 + 4];
        bf16x8 xf;
        xf[0] = (short)f32_to_bf16(a0.x); xf[1] = (short)f32_to_bf16(a0.y);
        xf[2] = (short)f32_to_bf16(a0.z); xf[3] = (short)f32_to_bf16(a0.w);
        xf[4] = (short)f32_to_bf16(a1.x); xf[5] = (short)f32_to_bf16(a1.y);
        xf[6] = (short)f32_to_bf16(a1.z); xf[7] = (short)f32_to_bf16(a1.w);
#pragma unroll
        for (int nt = 0; nt < 8; ++nt) {
            const bf16x8 wf = *(const bf16x8*)&Wl[((nt * 16 + m) * HID + k0) ^ swz];
            acc[nt] = __builtin_amdgcn_mfma_f32_16x16x32_bf16(wf, xf, acc[nt], 0, 0, 0);
        }
    }

    const int srow = row0 + m;
    const bool ok = srow < N_ITEMS;
#pragma unroll
    for (int nt = 0; nt < 8; ++nt) {
        const int c0 = nt * 16 + q * 4;         // 4 consecutive out cols
        float4 bv = *(const float4*)&bias[c0];
        ushort_t h0 = __half_as_ushort(__float2half(acc[nt][0] + bv.x));
        ushort_t h1 = __half_as_ushort(__float2half(acc[nt][1] + bv.y));
        ushort_t h2 = __half_as_ushort(__float2half(acc[nt][2] + bv.z));
        ushort_t h3 = __half_as_ushort(__float2half(acc[nt][3] + bv.w));
        uint2 pk;
        pk.x = (uint_t)h0 | ((uint_t)h1 << 16);
        pk.y = (uint_t)h2 | ((uint_t)h3 << 16);
        if (ok) *(uint2*)&S[(size_t)srow * HID + c0] = pk;
    }
}

// === K2: out[row] = sum vals*S[cols] (fp16 S), persistent grid-stride version.
// Each wave owns ~6 row-pairs; next pair's row_ptr and next window's cols/vals
// are issued before the current window's gathers are consumed, so latency
// chains overlap. Accumulation structure identical to the passing kernel
// (fp16 partials per edge-quad, f32 cross-group reduce) -> same numerics.
__global__ __launch_bounds__(256) void spmm_csr(
    const int* __restrict__ cols, const float* __restrict__ vals,
    const int* __restrict__ row_ptr, const ushort_t* __restrict__ S,
    float* __restrict__ out) {
    const int lane = threadIdx.x & 63;
    const int g = lane >> 4;                    // edge slot within a quad (0..3)
    const int l = lane & 15;                    // column octet: cols 8*l .. 8*l+7
    const int sel = lane >> 5;                  // 0: window A, 1: window B
    const int NP = N_ITEMS / 2;

    int wid = blockIdx.x * 4 + (threadIdx.x >> 6);
    if (wid >= NP) return;
    int2 p01 = *(const int2*)&row_ptr[wid * 2];
    int pE2 = row_ptr[wid * 2 + 2];

    for (;;) {
        const int nwid = wid + WSTRIDE;
        const bool has_next = (nwid < NP);
        int2 np01 = p01; int npE2 = pE2;
        if (has_next) {                         // prefetch next pair's ptrs now
            np01 = *(const int2*)&row_ptr[nwid * 2];
            npE2 = row_ptr[nwid * 2 + 2];
        }

        int pa = p01.x; const int pEa = p01.y;
        int pb = p01.y; const int pEb = pE2;

        __half2 accA[4], accB[4];
#pragma unroll
        for (int j = 0; j < 4; ++j) { accA[j] = __float2half2_rn(0.f); accB[j] = __float2half2_rn(0.f); }

        if (pa < pEa || pb < pEb) {
            // preload first window (one coalesced load fills both rows' slots)
            const int base = sel ? pb : pa;
            const int end  = sel ? pEb : pEa;
            const int idx  = base + l;
            const int cidx = max(min(idx, end - 1), 0);   // clamp (empty-row safe)
            int   c_l = cols[cidx];
            float v_l = (idx < end) ? vals[cidx] : 0.f;

            for (;;) {
                const int pa2 = min(pa + 16, pEa);
                const int pb2 = min(pb + 16, pEb);
                const bool more = (pa2 < pEa) || (pb2 < pEb);   // wave-uniform
                int c_n = 0; float v_n = 0.f;
                if (more) {                      // issue next window's loads early
                    const int b2 = sel ? pb2 : pa2;
                    const int e2 = sel ? pEb : pEa;
                    const int i2 = b2 + l;
                    const int ci2 = max(min(i2, e2 - 1), 0);
                    c_n = cols[ci2];
                    v_n = (i2 < e2) ? vals[ci2] : 0.f;
                }

                uint4 uA[4], uB[4];
                float vA[4], vB[4];
#pragma unroll
                for (int t = 0; t < 4; ++t) {    // 8 quad-gathers in flight
                    const int sa = 4 * t + g;
                    const int ca = __shfl(c_l, sa, 64);
                    vA[t] = __shfl(v_l, sa, 64);
                    uA[t] = *(const uint4*)&S[(size_t)ca * HID + 8 * l];
                    const int cb = __shfl(c_l, 32 + sa, 64);
                    vB[t] = __shfl(v_l, 32 + sa, 64);
                    uB[t] = *(const uint4*)&S[(size_t)cb * HID + 8 * l];
                }
#pragma unroll
                for (int t = 0; t < 4; ++t) {
                    const __half2 wa = __float2half2_rn(vA[t]);
                    accA[0] = __hfma2(wa, *(const __half2*)&uA[t].x, accA[0]);
                    accA[1] = __hfma2(wa, *(const __half2*)&uA[t].y, accA[1]);
                    accA[2] = __hfma2(wa, *(const __half2*)&uA[t].z, accA[2]);
                    accA[3] = __hfma2(wa, *(const __half2*)&uA[t].w, accA[3]);
                    const __half2 wb = __float2half2_rn(vB[t]);
                    accB[0] = __hfma2(wb, *(const __half2*)&uB[t].x, accB[0]);
                    accB[1] = __hfma2(wb, *(const __half2*)&uB[t].y, accB[1]);
                    accB[2] = __hfma2(wb, *(const __half2*)&uB[t].z, accB[2]);
                    accB[3] = __hfma2(wb, *(const __half2*)&uB[t].w, accB[3]);
                }
                if (!more) break;
                pa = pa2; pb = pb2; c_l = c_n; v_l = v_n;
            }
        }

        // unpack to f32; xor-reduce over the 4 edge-groups; store
        float fA[8], fB[8];
#pragma unroll
        for (int j = 0; j < 4; ++j) {
            fA[2 * j] = __low2float(accA[j]);  fA[2 * j + 1] = __high2float(accA[j]);
            fB[2 * j] = __low2float(accB[j]);  fB[2 * j + 1] = __high2float(accB[j]);
        }
#pragma unroll
        for (int e = 0; e < 8; ++e) {
            fA[e] += __shfl_xor(fA[e], 16, 64);
            fA[e] += __shfl_xor(fA[e], 32, 64);
            fB[e] += __shfl_xor(fB[e], 16, 64);
            fB[e] += __shfl_xor(fB[e], 32, 64);
        }
        const int r0 = wid * 2;
        if (g == 0) {                            // lanes 0-15: row A
            float* p = &out[(size_t)r0 * HID + 8 * l];
            *(float4*)p       = make_float4(fA[0], fA[1], fA[2], fA[3]);
            *(float4*)(p + 4) = make_float4(fA[4], fA[5], fA[6], fA[7]);
        } else if (g == 1 && r0 + 1 < N_ITEMS) { // lanes 16-31: row B
            float* p = &out[(size_t)(r0 + 1) * HID + 8 * l];
            *(float4*)p       = make_float4(fB[0], fB[1], fB[2], fB[3]);
            *(float4*)(p + 4) = make_float4(fB[4], fB[5], fB[6], fB[7]);
        }

        if (!has_next) break;
        wid = nwid; p01 = np01; pE2 = npE2;
    }
}

extern "C" void kernel_launch(void* const* d_in, const int* in_sizes, int n_in,
                              void* d_out, int out_size, void* d_ws, size_t ws_size,
                              hipStream_t stream) {
    const float* X    = (const float*)d_in[0];
    const int*   rows = (const int*)  d_in[1];
    const int*   cols = (const int*)  d_in[2];
    const float* vals = (const float*)d_in[3];
    const float* W    = (const float*)d_in[4];
    const float* bias = (const float*)d_in[5];
    float* out = (float*)d_out;

    ushort_t* S       = (ushort_t*)d_ws;                    // 25.6 MB (fp16)
    int*      row_ptr = (int*)(S + (size_t)N_ITEMS * HID);  // 400 KB

    prep_gemm<<<RP_BLOCKS + GB_BLOCKS, 256, 0, stream>>>(X, W, bias, rows, S, row_ptr);
    spmm_csr<<<SPMM_BLOCKS, 256, 0, stream>>>(cols, vals, row_ptr, S, out);
}